// Round 5
// baseline (3590.572 us; speedup 1.0000x reference)
//
#include <hip/hip_runtime.h>
#include <hip/hip_fp16.h>

#define NPART 131072
#define QDIM 32
#define DDIM 64
#define HDIM 50
#define STEPS 16
#define DT 0.1f
#define LN_EPS 1e-5f
#define INV_H 0.02f   // 1/50
#define ODIM 65       // output row stride

typedef float f4a __attribute__((ext_vector_type(4)));              // aligned 16 (loads)
typedef float f4u __attribute__((ext_vector_type(4), aligned(4)));  // 4B-aligned ld/st

// ---- f16 pair pack/unpack (x2 in low half, tw in high half) ----
__device__ __forceinline__ float pack2h(float x, float t) {
    const unsigned hx = __half_as_ushort(__float2half_rn(x));
    const unsigned ht = __half_as_ushort(__float2half_rn(t));
    return __uint_as_float((ht << 16) | hx);
}
__device__ __forceinline__ void unpack_lo(float f, float& x) {
    const unsigned u = __float_as_uint(f);
    x = __half2float(__ushort_as_half((unsigned short)(u & 0xffff)));
}
__device__ __forceinline__ void unpack2h(float f, float& x, float& t) {
    const unsigned u = __float_as_uint(f);
    x = __half2float(__ushort_as_half((unsigned short)(u & 0xffff)));
    t = __half2float(__ushort_as_half((unsigned short)(u >> 16)));
}

// ---------------- setup: W1T, W2T, UT, M, svec into d_ws ----------------
__global__ void ode2vae_setup(const float* __restrict__ W1,
                              const float* __restrict__ W2,
                              const float* __restrict__ W3,
                              float* __restrict__ ws)
{
    const int tid = threadIdx.x;
    float* W1T = ws;           // 50x64
    float* W2T = ws + 3200;    // 50x50  W2T[j][h] = W2[h][j]
    float* UT  = ws + 5700;    // 50x50  UT[j][h]  = sum_i W1[i][h]*W3[j][i]
    float* M   = ws + 8200;    // 50x50  M = UT .* (W2T - w2rs/H)
    float* sv  = ws + 10700;   // 50     sv[j] = sum_h UT[j][h]
    for (int idx = tid; idx < HDIM * DDIM; idx += 256) {
        const int h = idx / DDIM, d = idx % DDIM;
        W1T[idx] = W1[d * HDIM + h];
    }
    for (int idx = tid; idx < HDIM * HDIM; idx += 256) {
        const int j = idx / HDIM, h = idx % HDIM;
        float u = 0.f;
        #pragma unroll
        for (int i = 0; i < QDIM; ++i)
            u = fmaf(W1[i * HDIM + h], W3[j * QDIM + i], u);
        const float w2 = W2[h * HDIM + j];
        float rs = 0.f;
        for (int jj = 0; jj < HDIM; ++jj) rs += W2[h * HDIM + jj];
        W2T[idx] = w2;
        UT[idx]  = u;
        M[idx]   = u * (w2 - INV_H * rs);
    }
    if (tid < HDIM) {
        float acc = 0.f;
        #pragma unroll
        for (int i = 0; i < QDIM; ++i) {
            float rs1 = 0.f;
            for (int h = 0; h < HDIM; ++h) rs1 += W1[i * HDIM + h];
            acc = fmaf(rs1, W3[tid * QDIM + i], acc);
        }
        sv[tid] = acc;
    }
}

// 4-way partial 50-dot: r (uniform row) . v (register array)
#define DOT50(res, r, v)                                             \
    {                                                                \
        float p0 = 0.f, p1 = 0.f, p2 = 0.f, p3 = 0.f;                \
        _Pragma("unroll")                                            \
        for (int h_ = 0; h_ < 48; h_ += 4) {                         \
            p0 = fmaf((r)[h_],     (v)[h_],     p0);                 \
            p1 = fmaf((r)[h_ + 1], (v)[h_ + 1], p1);                 \
            p2 = fmaf((r)[h_ + 2], (v)[h_ + 2], p2);                 \
            p3 = fmaf((r)[h_ + 3], (v)[h_ + 3], p3);                 \
        }                                                            \
        p0 = fmaf((r)[48], (v)[48], p0);                             \
        p1 = fmaf((r)[49], (v)[49], p1);                             \
        res = (p0 + p1) + (p2 + p3);                                 \
    }

__global__ __launch_bounds__(64, 3)
void ode2vae_main(const float* __restrict__ z0, const float* __restrict__ logp0,
                  const float* __restrict__ b1, const float* __restrict__ g1,
                  const float* __restrict__ be1,
                  const float* __restrict__ b2, const float* __restrict__ g2,
                  const float* __restrict__ be2,
                  const float* __restrict__ W3, const float* __restrict__ b3,
                  const float* __restrict__ W1T, const float* __restrict__ W2T,
                  const float* __restrict__ UT, const float* __restrict__ M,
                  const float* __restrict__ svec,
                  float* out)                      // no __restrict__: we read our own writes
{
    // ONE 50-slot per-lane LDS array, slot-major [slot][64]:
    // a1 raw -> a2 raw -> packed f16(x2, tw)
    __shared__ float lds[HDIM * 64];
    const int lane = threadIdx.x;
    const int n = blockIdx.x * 64 + lane;
    float* const L = lds + lane;
#define SLOT(k) L[(k) * 64]

    // zq persists in registers; zs round-trips through `out`; lp persists.
    float zq[QDIM];
    {
        const f4a* zp = (const f4a*)(z0 + (size_t)n * DDIM);
        #pragma unroll
        for (int k = 0; k < 8; ++k) {
            f4a v = zp[k];
            zq[4 * k]     = v[0]; zq[4 * k + 1] = v[1];
            zq[4 * k + 2] = v[2]; zq[4 * k + 3] = v[3];
        }
    }
    float lp = logp0[n];

    for (int s = 0; s < STEPS; ++s) {
        float* const odst = out + ((size_t)s * NPART + (size_t)n) * ODIM;

        // ======== phase A: load zs, a1 -> LDS, zs update+store ========
        float zs[QDIM];
        {
            const float* zssrc = (s == 0)
                ? (z0 + (size_t)n * DDIM + QDIM)
                : (out + ((size_t)(s - 1) * NPART + (size_t)n) * ODIM + QDIM);
            #pragma unroll
            for (int k = 0; k < 8; ++k) {
                f4u v = *(const f4u*)(zssrc + 4 * k);
                zs[4 * k]     = v[0]; zs[4 * k + 1] = v[1];
                zs[4 * k + 2] = v[2]; zs[4 * k + 3] = v[3];
            }
        }
        float m1a = 0.f, v1a = 0.f;
        #pragma unroll 1
        for (int h = 0; h < HDIM; ++h) {
            const float* __restrict__ r = W1T + h * DDIM;
            float p0 = 0.f, p1 = 0.f, p2 = 0.f, p3 = 0.f;
            #pragma unroll
            for (int d = 0; d < QDIM; d += 4) {
                p0 = fmaf(r[d],     zq[d],     p0);
                p1 = fmaf(r[d + 1], zq[d + 1], p1);
                p2 = fmaf(r[d + 2], zq[d + 2], p2);
                p3 = fmaf(r[d + 3], zq[d + 3], p3);
            }
            #pragma unroll
            for (int d = 0; d < QDIM; d += 4) {
                p0 = fmaf(r[QDIM + d],     zs[d],     p0);
                p1 = fmaf(r[QDIM + d + 1], zs[d + 1], p1);
                p2 = fmaf(r[QDIM + d + 2], zs[d + 2], p2);
                p3 = fmaf(r[QDIM + d + 3], zs[d + 3], p3);
            }
            const float a1h = ((p0 + p1) + (p2 + p3)) + b1[h];
            SLOT(h) = a1h;
            m1a += a1h;
            v1a = fmaf(a1h, a1h, v1a);
        }
        // zs_new = zs_old + DT*zq_old; store now, free the registers
        #pragma unroll
        for (int k = 0; k < QDIM; ++k) zs[k] = fmaf(DT, zq[k], zs[k]);
        #pragma unroll
        for (int k = 0; k < 8; ++k) {
            f4u v = {zs[4*k], zs[4*k+1], zs[4*k+2], zs[4*k+3]};
            *(f4u*)(odst + QDIM + 4 * k) = v;
        }
        const float m1 = m1a * INV_H;
        float var1 = v1a * INV_H - m1 * m1;
        var1 = var1 > 0.f ? var1 : 0.f;
        const float r1 = rsqrtf(var1 + LN_EPS);

        // ======== B: xh1, hh from LDS a1 ========
        float xh1[HDIM], hh[HDIM];
        #pragma unroll
        for (int h = 0; h < HDIM; ++h) {
            const float xh = (SLOT(h) - m1) * r1;
            xh1[h] = xh;
            const float y = fmaf(xh, g1[h], be1[h]);
            const float e = __expf(y);
            hh[h] = (y > 0.f) ? y : (e - 1.f);            // celu
        }

        // ======== C: a2 rolled j (dots over hh) -> LDS ========
        float m2a = 0.f, v2a = 0.f;
        #pragma unroll 1
        for (int j = 0; j < HDIM; ++j) {
            const float* __restrict__ r = W2T + j * HDIM;
            float a2j;
            DOT50(a2j, r, hh);
            a2j += b2[j];
            SLOT(j) = a2j;
            m2a += a2j;
            v2a = fmaf(a2j, a2j, v2a);
        }
        const float m2 = m2a * INV_H;
        float var2 = v2a * INV_H - m2 * m2;
        var2 = var2 > 0.f ? var2 : 0.f;
        const float r2 = rsqrtf(var2 + LN_EPS);

        // ======== D1: x2, t, tw; pack in place; scalar sums ========
        float suA = 0.f, syA = 0.f, tuA = 0.f, tyA = 0.f;
        #pragma unroll 1
        for (int j = 0; j < HDIM; ++j) {
            const float x2 = (SLOT(j) - m2) * r2;
            const float* __restrict__ r = UT + j * HDIM;
            float t;
            DOT50(t, r, xh1);
            const float g2j = g2[j];
            const float y = fmaf(x2, g2j, be2[j]);
            const float e = __expf(y);
            const float w2vj = ((y > 0.f) ? 1.f : e) * (g2j * r2);
            const float tw = w2vj * t;
            SLOT(j) = pack2h(x2, tw);
            tuA += tw; tyA = fmaf(tw, x2, tyA);
            const float sw = svec[j] * w2vj;
            suA += sw; syA = fmaf(sw, x2, syA);
        }
        const float suH = suA * INV_H, syH = syA * INV_H;
        const float tuH = tuA * INV_H, tyH = tyA * INV_H;

        // ======== G: w1v; xh1 -> w1x in place (hh dead) ========
        float w1v[HDIM];
        #pragma unroll
        for (int h = 0; h < HDIM; ++h) {
            const float gg = g1[h];
            const float y = fmaf(xh1[h], gg, be1[h]);
            const float e = __expf(y);
            const float w = ((y > 0.f) ? 1.f : e) * (gg * r1);
            w1v[h] = w;
            xh1[h] *= w;                                   // w1x
        }

        // ======== F1: S2 (w1v), S3 (w1x) over W2T rows ========
        float S2 = 0.f, S3 = 0.f;
        #pragma unroll 1
        for (int j = 0; j < HDIM; ++j) {
            const float* __restrict__ r = W2T + j * HDIM;
            float x2, tw; unpack2h(SLOT(j), x2, tw);
            const float g2j = g2[j];
            const float y = fmaf(x2, g2j, be2[j]);
            const float e = __expf(y);
            const float w2vj = ((y > 0.f) ? 1.f : e) * (g2j * r2);
            const float q1 = fmaf(-syH, x2, svec[j] * w2vj - suH);
            const float q2 = fmaf(-tyH, x2, tw - tuH);
            float c10 = 0.f, c11 = 0.f, c30 = 0.f, c31 = 0.f;
            #pragma unroll
            for (int h = 0; h < HDIM; h += 2) {
                c10 = fmaf(r[h],   w1v[h],   c10);
                c11 = fmaf(r[h+1], w1v[h+1], c11);
                c30 = fmaf(r[h],   xh1[h],   c30);   // w1x
                c31 = fmaf(r[h+1], xh1[h+1], c31);
            }
            S2 = fmaf(q1, c10 + c11, S2);
            S3 = fmaf(q2, c30 + c31, S3);
        }

        // ======== T1A: M rows . w1v (w1x dead) ========
        float T1A = 0.f;
        #pragma unroll 1
        for (int j = 0; j < HDIM; ++j) {
            const float* __restrict__ r = M + j * HDIM;
            float x2; unpack_lo(SLOT(j), x2);
            const float g2j = g2[j];
            const float y = fmaf(x2, g2j, be2[j]);
            const float e = __expf(y);
            const float w2vj = ((y > 0.f) ? 1.f : e) * (g2j * r2);
            float cv;
            DOT50(cv, r, w1v);
            T1A = fmaf(w2vj, cv, T1A);
        }

        // ======== F2: duy accumulation over UT rows ========
        float duy[HDIM];
        #pragma unroll
        for (int h = 0; h < HDIM; ++h) duy[h] = 0.f;
        #pragma unroll 1
        for (int j = 0; j < HDIM; ++j) {
            const float* __restrict__ r = UT + j * HDIM;
            float x2; unpack_lo(SLOT(j), x2);
            const float g2j = g2[j];
            const float y = fmaf(x2, g2j, be2[j]);
            const float e = __expf(y);
            const float w2vj = ((y > 0.f) ? 1.f : e) * (g2j * r2);
            const float y3 = x2 * w2vj;
            #pragma unroll
            for (int h = 0; h < HDIM; ++h)
                duy[h] = fmaf(r[h], y3, duy[h]);
        }
        // wduy in place (w1v dies after this)
        #pragma unroll
        for (int h = 0; h < HDIM; ++h) duy[h] *= w1v[h];

        // ======== T1c: W2T rows . wduy ========
        float T1c = 0.f;
        #pragma unroll 1
        for (int j = 0; j < HDIM; ++j) {
            const float* __restrict__ r = W2T + j * HDIM;
            float x2; unpack_lo(SLOT(j), x2);
            float cT;
            DOT50(cT, r, duy);
            T1c = fmaf(x2, cT, T1c);
        }
        const float tr = T1A - (T1c + S2 + S3) * INV_H;

        // ======== dv = h2 @ W3 + b3 ========
        float dv[QDIM];
        #pragma unroll
        for (int i = 0; i < QDIM; ++i) dv[i] = b3[i];
        #pragma unroll 1
        for (int j = 0; j < HDIM; ++j) {
            float x2; unpack_lo(SLOT(j), x2);
            const float y = fmaf(x2, g2[j], be2[j]);
            const float e = __expf(y);
            const float h2 = (y > 0.f) ? y : (e - 1.f);
            const float* __restrict__ r = W3 + j * QDIM;
            #pragma unroll
            for (int i = 0; i < QDIM; ++i) dv[i] = fmaf(h2, r[i], dv[i]);
        }

        // ======== update zq, lp; store ========
        lp = fmaf(-DT, tr, lp);
        #pragma unroll
        for (int i = 0; i < QDIM; ++i) zq[i] = fmaf(DT, dv[i], zq[i]);
        #pragma unroll
        for (int k = 0; k < 8; ++k) {
            f4u v = {zq[4*k], zq[4*k+1], zq[4*k+2], zq[4*k+3]};
            *(f4u*)(odst + 4 * k) = v;
        }
        odst[DDIM] = lp;
    }
}

extern "C" void kernel_launch(void* const* d_in, const int* in_sizes, int n_in,
                              void* d_out, int out_size, void* d_ws, size_t ws_size,
                              hipStream_t stream)
{
    const float* z0    = (const float*)d_in[0];
    const float* logp0 = (const float*)d_in[1];
    const float* W1    = (const float*)d_in[2];
    const float* b1    = (const float*)d_in[3];
    const float* g1    = (const float*)d_in[4];
    const float* be1   = (const float*)d_in[5];
    const float* W2    = (const float*)d_in[6];
    const float* b2    = (const float*)d_in[7];
    const float* g2    = (const float*)d_in[8];
    const float* be2   = (const float*)d_in[9];
    const float* W3    = (const float*)d_in[10];
    const float* b3    = (const float*)d_in[11];
    float* out = (float*)d_out;
    float* ws  = (float*)d_ws;

    hipLaunchKernelGGL(ode2vae_setup, dim3(1), dim3(256), 0, stream, W1, W2, W3, ws);

    const float* W1T  = ws;
    const float* W2T  = ws + 3200;
    const float* UT   = ws + 5700;
    const float* Mm   = ws + 8200;
    const float* svec = ws + 10700;

    hipLaunchKernelGGL(ode2vae_main, dim3(NPART / 64), dim3(64), 0, stream,
                       z0, logp0, b1, g1, be1, b2, g2, be2, W3, b3,
                       W1T, W2T, UT, Mm, svec, out);
}

// Round 6
// 2422.632 us; speedup vs baseline: 1.4821x; 1.4821x over previous
//
#include <hip/hip_runtime.h>
#include <hip/hip_fp16.h>

#define NPART 131072
#define QDIM 32
#define DDIM 64
#define HDIM 50
#define STEPS 16
#define DT 0.1f
#define LN_EPS 1e-5f
#define INV_H 0.02f   // 1/50
#define ODIM 65       // output row stride

typedef float f4a __attribute__((ext_vector_type(4)));              // aligned 16 (loads)
typedef float f4u __attribute__((ext_vector_type(4), aligned(4)));  // 4B-aligned ld/st

// ---- f16 pair pack/unpack (x2 in low half, tw in high half) ----
__device__ __forceinline__ float pack2h(float x, float t) {
    const unsigned hx = __half_as_ushort(__float2half_rn(x));
    const unsigned ht = __half_as_ushort(__float2half_rn(t));
    return __uint_as_float((ht << 16) | hx);
}
__device__ __forceinline__ void unpack_lo(float f, float& x) {
    const unsigned u = __float_as_uint(f);
    x = __half2float(__ushort_as_half((unsigned short)(u & 0xffff)));
}
__device__ __forceinline__ void unpack2h(float f, float& x, float& t) {
    const unsigned u = __float_as_uint(f);
    x = __half2float(__ushort_as_half((unsigned short)(u & 0xffff)));
    t = __half2float(__ushort_as_half((unsigned short)(u >> 16)));
}

// ---------------- setup: W1T, W2T, UT, M, svec into d_ws ----------------
__global__ void ode2vae_setup(const float* __restrict__ W1,
                              const float* __restrict__ W2,
                              const float* __restrict__ W3,
                              float* __restrict__ ws)
{
    const int tid = threadIdx.x;
    float* W1T = ws;           // 50x64
    float* W2T = ws + 3200;    // 50x50  W2T[j][h] = W2[h][j]
    float* UT  = ws + 5700;    // 50x50  UT[j][h]  = sum_i W1[i][h]*W3[j][i]
    float* M   = ws + 8200;    // 50x50  M = UT .* (W2T - w2rs/H)
    float* sv  = ws + 10700;   // 50     sv[j] = sum_h UT[j][h]
    for (int idx = tid; idx < HDIM * DDIM; idx += 256) {
        const int h = idx / DDIM, d = idx % DDIM;
        W1T[idx] = W1[d * HDIM + h];
    }
    for (int idx = tid; idx < HDIM * HDIM; idx += 256) {
        const int j = idx / HDIM, h = idx % HDIM;
        float u = 0.f;
        #pragma unroll
        for (int i = 0; i < QDIM; ++i)
            u = fmaf(W1[i * HDIM + h], W3[j * QDIM + i], u);
        const float w2 = W2[h * HDIM + j];
        float rs = 0.f;
        for (int jj = 0; jj < HDIM; ++jj) rs += W2[h * HDIM + jj];
        W2T[idx] = w2;
        UT[idx]  = u;
        M[idx]   = u * (w2 - INV_H * rs);
    }
    if (tid < HDIM) {
        float acc = 0.f;
        #pragma unroll
        for (int i = 0; i < QDIM; ++i) {
            float rs1 = 0.f;
            for (int h = 0; h < HDIM; ++h) rs1 += W1[i * HDIM + h];
            acc = fmaf(rs1, W3[tid * QDIM + i], acc);
        }
        sv[tid] = acc;
    }
}

// 4-way partial 50-dot: r (uniform row) . v (register array)
#define DOT50(res, r, v)                                             \
    {                                                                \
        float p0 = 0.f, p1 = 0.f, p2 = 0.f, p3 = 0.f;                \
        _Pragma("unroll")                                            \
        for (int h_ = 0; h_ < 48; h_ += 4) {                         \
            p0 = fmaf((r)[h_],     (v)[h_],     p0);                 \
            p1 = fmaf((r)[h_ + 1], (v)[h_ + 1], p1);                 \
            p2 = fmaf((r)[h_ + 2], (v)[h_ + 2], p2);                 \
            p3 = fmaf((r)[h_ + 3], (v)[h_ + 3], p3);                 \
        }                                                            \
        p0 = fmaf((r)[48], (v)[48], p0);                             \
        p1 = fmaf((r)[49], (v)[49], p1);                             \
        res = (p0 + p1) + (p2 + p3);                                 \
    }

__global__ __launch_bounds__(64, 1)
void ode2vae_main(const float* __restrict__ z0, const float* __restrict__ logp0,
                  const float* __restrict__ b1, const float* __restrict__ g1,
                  const float* __restrict__ be1,
                  const float* __restrict__ b2, const float* __restrict__ g2,
                  const float* __restrict__ be2,
                  const float* __restrict__ W3, const float* __restrict__ b3,
                  const float* __restrict__ W1T, const float* __restrict__ W2T,
                  const float* __restrict__ UT, const float* __restrict__ M,
                  const float* __restrict__ svec,
                  float* out)                      // no __restrict__: we read our own writes
{
    // ONE 50-slot per-lane LDS array, slot-major [slot][64]:
    // a1 raw -> a2 raw -> packed f16(x2, tw)
    __shared__ float lds[HDIM * 64];
    const int lane = threadIdx.x;
    const int n = blockIdx.x * 64 + lane;
    float* const L = lds + lane;
#define SLOT(k) L[(k) * 64]

    // zq persists in registers; zs round-trips through `out`; lp persists.
    float zq[QDIM];
    {
        const f4a* zp = (const f4a*)(z0 + (size_t)n * DDIM);
        #pragma unroll
        for (int k = 0; k < 8; ++k) {
            f4a v = zp[k];
            zq[4 * k]     = v[0]; zq[4 * k + 1] = v[1];
            zq[4 * k + 2] = v[2]; zq[4 * k + 3] = v[3];
        }
    }
    float lp = logp0[n];

    for (int s = 0; s < STEPS; ++s) {
        float* const odst = out + ((size_t)s * NPART + (size_t)n) * ODIM;

        // ======== phase A: load zs, a1 -> LDS, zs update+store ========
        float zs[QDIM];
        {
            const float* zssrc = (s == 0)
                ? (z0 + (size_t)n * DDIM + QDIM)
                : (out + ((size_t)(s - 1) * NPART + (size_t)n) * ODIM + QDIM);
            #pragma unroll
            for (int k = 0; k < 8; ++k) {
                f4u v = *(const f4u*)(zssrc + 4 * k);
                zs[4 * k]     = v[0]; zs[4 * k + 1] = v[1];
                zs[4 * k + 2] = v[2]; zs[4 * k + 3] = v[3];
            }
        }
        float m1a = 0.f, v1a = 0.f;
        #pragma unroll 1
        for (int h = 0; h < HDIM; ++h) {
            const float* __restrict__ r = W1T + h * DDIM;
            float p0 = 0.f, p1 = 0.f, p2 = 0.f, p3 = 0.f;
            #pragma unroll
            for (int d = 0; d < QDIM; d += 4) {
                p0 = fmaf(r[d],     zq[d],     p0);
                p1 = fmaf(r[d + 1], zq[d + 1], p1);
                p2 = fmaf(r[d + 2], zq[d + 2], p2);
                p3 = fmaf(r[d + 3], zq[d + 3], p3);
            }
            #pragma unroll
            for (int d = 0; d < QDIM; d += 4) {
                p0 = fmaf(r[QDIM + d],     zs[d],     p0);
                p1 = fmaf(r[QDIM + d + 1], zs[d + 1], p1);
                p2 = fmaf(r[QDIM + d + 2], zs[d + 2], p2);
                p3 = fmaf(r[QDIM + d + 3], zs[d + 3], p3);
            }
            const float a1h = ((p0 + p1) + (p2 + p3)) + b1[h];
            SLOT(h) = a1h;
            m1a += a1h;
            v1a = fmaf(a1h, a1h, v1a);
        }
        // zs_new = zs_old + DT*zq_old; store now, free the registers
        #pragma unroll
        for (int k = 0; k < QDIM; ++k) zs[k] = fmaf(DT, zq[k], zs[k]);
        #pragma unroll
        for (int k = 0; k < 8; ++k) {
            f4u v = {zs[4*k], zs[4*k+1], zs[4*k+2], zs[4*k+3]};
            *(f4u*)(odst + QDIM + 4 * k) = v;
        }
        const float m1 = m1a * INV_H;
        float var1 = v1a * INV_H - m1 * m1;
        var1 = var1 > 0.f ? var1 : 0.f;
        const float r1 = rsqrtf(var1 + LN_EPS);

        // ======== B: xh1, hh from LDS a1 ========
        float xh1[HDIM], hh[HDIM];
        #pragma unroll
        for (int h = 0; h < HDIM; ++h) {
            const float xh = (SLOT(h) - m1) * r1;
            xh1[h] = xh;
            const float y = fmaf(xh, g1[h], be1[h]);
            const float e = __expf(y);
            hh[h] = (y > 0.f) ? y : (e - 1.f);            // celu
        }

        // ======== C: a2 rolled j (dots over hh) -> LDS ========
        float m2a = 0.f, v2a = 0.f;
        #pragma unroll 1
        for (int j = 0; j < HDIM; ++j) {
            const float* __restrict__ r = W2T + j * HDIM;
            float a2j;
            DOT50(a2j, r, hh);
            a2j += b2[j];
            SLOT(j) = a2j;
            m2a += a2j;
            v2a = fmaf(a2j, a2j, v2a);
        }
        const float m2 = m2a * INV_H;
        float var2 = v2a * INV_H - m2 * m2;
        var2 = var2 > 0.f ? var2 : 0.f;
        const float r2 = rsqrtf(var2 + LN_EPS);

        // ======== D1: x2, t, tw; pack in place; scalar sums ========
        float suA = 0.f, syA = 0.f, tuA = 0.f, tyA = 0.f;
        #pragma unroll 1
        for (int j = 0; j < HDIM; ++j) {
            const float x2 = (SLOT(j) - m2) * r2;
            const float* __restrict__ r = UT + j * HDIM;
            float t;
            DOT50(t, r, xh1);
            const float g2j = g2[j];
            const float y = fmaf(x2, g2j, be2[j]);
            const float e = __expf(y);
            const float w2vj = ((y > 0.f) ? 1.f : e) * (g2j * r2);
            const float tw = w2vj * t;
            SLOT(j) = pack2h(x2, tw);
            tuA += tw; tyA = fmaf(tw, x2, tyA);
            const float sw = svec[j] * w2vj;
            suA += sw; syA = fmaf(sw, x2, syA);
        }
        const float suH = suA * INV_H, syH = syA * INV_H;
        const float tuH = tuA * INV_H, tyH = tyA * INV_H;

        // ======== G: w1v; xh1 -> w1x in place (hh dead) ========
        float w1v[HDIM];
        #pragma unroll
        for (int h = 0; h < HDIM; ++h) {
            const float gg = g1[h];
            const float y = fmaf(xh1[h], gg, be1[h]);
            const float e = __expf(y);
            const float w = ((y > 0.f) ? 1.f : e) * (gg * r1);
            w1v[h] = w;
            xh1[h] *= w;                                   // w1x
        }

        // ======== F1: S2 (w1v), S3 (w1x) over W2T rows ========
        float S2 = 0.f, S3 = 0.f;
        #pragma unroll 1
        for (int j = 0; j < HDIM; ++j) {
            const float* __restrict__ r = W2T + j * HDIM;
            float x2, tw; unpack2h(SLOT(j), x2, tw);
            const float g2j = g2[j];
            const float y = fmaf(x2, g2j, be2[j]);
            const float e = __expf(y);
            const float w2vj = ((y > 0.f) ? 1.f : e) * (g2j * r2);
            const float q1 = fmaf(-syH, x2, svec[j] * w2vj - suH);
            const float q2 = fmaf(-tyH, x2, tw - tuH);
            float c10 = 0.f, c11 = 0.f, c30 = 0.f, c31 = 0.f;
            #pragma unroll
            for (int h = 0; h < HDIM; h += 2) {
                c10 = fmaf(r[h],   w1v[h],   c10);
                c11 = fmaf(r[h+1], w1v[h+1], c11);
                c30 = fmaf(r[h],   xh1[h],   c30);   // w1x
                c31 = fmaf(r[h+1], xh1[h+1], c31);
            }
            S2 = fmaf(q1, c10 + c11, S2);
            S3 = fmaf(q2, c30 + c31, S3);
        }

        // ======== T1A: M rows . w1v (w1x dead) ========
        float T1A = 0.f;
        #pragma unroll 1
        for (int j = 0; j < HDIM; ++j) {
            const float* __restrict__ r = M + j * HDIM;
            float x2; unpack_lo(SLOT(j), x2);
            const float g2j = g2[j];
            const float y = fmaf(x2, g2j, be2[j]);
            const float e = __expf(y);
            const float w2vj = ((y > 0.f) ? 1.f : e) * (g2j * r2);
            float cv;
            DOT50(cv, r, w1v);
            T1A = fmaf(w2vj, cv, T1A);
        }

        // ======== F2: duy accumulation over UT rows ========
        float duy[HDIM];
        #pragma unroll
        for (int h = 0; h < HDIM; ++h) duy[h] = 0.f;
        #pragma unroll 1
        for (int j = 0; j < HDIM; ++j) {
            const float* __restrict__ r = UT + j * HDIM;
            float x2; unpack_lo(SLOT(j), x2);
            const float g2j = g2[j];
            const float y = fmaf(x2, g2j, be2[j]);
            const float e = __expf(y);
            const float w2vj = ((y > 0.f) ? 1.f : e) * (g2j * r2);
            const float y3 = x2 * w2vj;
            #pragma unroll
            for (int h = 0; h < HDIM; ++h)
                duy[h] = fmaf(r[h], y3, duy[h]);
        }
        // wduy in place (w1v dies after this)
        #pragma unroll
        for (int h = 0; h < HDIM; ++h) duy[h] *= w1v[h];

        // ======== T1c: W2T rows . wduy ========
        float T1c = 0.f;
        #pragma unroll 1
        for (int j = 0; j < HDIM; ++j) {
            const float* __restrict__ r = W2T + j * HDIM;
            float x2; unpack_lo(SLOT(j), x2);
            float cT;
            DOT50(cT, r, duy);
            T1c = fmaf(x2, cT, T1c);
        }
        const float tr = T1A - (T1c + S2 + S3) * INV_H;

        // ======== dv = h2 @ W3 + b3 ========
        float dv[QDIM];
        #pragma unroll
        for (int i = 0; i < QDIM; ++i) dv[i] = b3[i];
        #pragma unroll 1
        for (int j = 0; j < HDIM; ++j) {
            float x2; unpack_lo(SLOT(j), x2);
            const float y = fmaf(x2, g2[j], be2[j]);
            const float e = __expf(y);
            const float h2 = (y > 0.f) ? y : (e - 1.f);
            const float* __restrict__ r = W3 + j * QDIM;
            #pragma unroll
            for (int i = 0; i < QDIM; ++i) dv[i] = fmaf(h2, r[i], dv[i]);
        }

        // ======== update zq, lp; store (zq/lp never reloaded -> nontemporal) ========
        lp = fmaf(-DT, tr, lp);
        #pragma unroll
        for (int i = 0; i < QDIM; ++i) zq[i] = fmaf(DT, dv[i], zq[i]);
        #pragma unroll
        for (int k = 0; k < 8; ++k) {
            f4u v = {zq[4*k], zq[4*k+1], zq[4*k+2], zq[4*k+3]};
            __builtin_nontemporal_store(v, (f4u*)(odst + 4 * k));
        }
        __builtin_nontemporal_store(lp, odst + DDIM);
    }
}

extern "C" void kernel_launch(void* const* d_in, const int* in_sizes, int n_in,
                              void* d_out, int out_size, void* d_ws, size_t ws_size,
                              hipStream_t stream)
{
    const float* z0    = (const float*)d_in[0];
    const float* logp0 = (const float*)d_in[1];
    const float* W1    = (const float*)d_in[2];
    const float* b1    = (const float*)d_in[3];
    const float* g1    = (const float*)d_in[4];
    const float* be1   = (const float*)d_in[5];
    const float* W2    = (const float*)d_in[6];
    const float* b2    = (const float*)d_in[7];
    const float* g2    = (const float*)d_in[8];
    const float* be2   = (const float*)d_in[9];
    const float* W3    = (const float*)d_in[10];
    const float* b3    = (const float*)d_in[11];
    float* out = (float*)d_out;
    float* ws  = (float*)d_ws;

    hipLaunchKernelGGL(ode2vae_setup, dim3(1), dim3(256), 0, stream, W1, W2, W3, ws);

    const float* W1T  = ws;
    const float* W2T  = ws + 3200;
    const float* UT   = ws + 5700;
    const float* Mm   = ws + 8200;
    const float* svec = ws + 10700;

    hipLaunchKernelGGL(ode2vae_main, dim3(NPART / 64), dim3(64), 0, stream,
                       z0, logp0, b1, g1, be1, b2, g2, be2, W3, b3,
                       W1T, W2T, UT, Mm, svec, out);
}